// Round 1
// 394.332 us; speedup vs baseline: 1.1009x; 1.1009x over previous
//
#include <hip/hip_runtime.h>
#include <stdint.h>

// Problem constants
#define BB   2
#define SS   2048
#define HID  2048
#define NHQ  16
#define NKV  8
#define DD   128
// QKV fused row layout: [q: 16*128 | k: 8*128 | v: 8*128] = 4096 bf16 per (b,s)
#define QKVW 4096

typedef __bf16 v8bf   __attribute__((ext_vector_type(8)));
typedef float  f32x4  __attribute__((ext_vector_type(4)));
typedef float  f32x16 __attribute__((ext_vector_type(16)));

__device__ __forceinline__ float bf2f(ushort u) {
    union { unsigned int i; float f; } x; x.i = ((unsigned int)u) << 16; return x.f;
}
__device__ __forceinline__ ushort f2bf(float f) {
    union { float f; unsigned int i; } x; x.f = f;
    unsigned int i = x.i;
    return (ushort)((i + 0x7fffu + ((i >> 16) & 1u)) >> 16); // RNE, finite inputs
}
__device__ __forceinline__ v8bf as_bf8(uint4 u) { return __builtin_bit_cast(v8bf, u); }

__device__ __forceinline__ unsigned int cvtpk_bf16(float lo, float hi) {
    unsigned int r;
    asm("v_cvt_pk_bf16_f32 %0, %1, %2" : "=v"(r) : "v"(lo), "v"(hi));
    return r;
}

__device__ __forceinline__ void store_el(float* p, float v)  { *p = v; }
__device__ __forceinline__ void store_el(ushort* p, float v) { *p = f2bf(v); }

// async global->LDS, 16B per lane; lds must be wave-uniform-base + lane*16
__device__ __forceinline__ void gll16(const ushort* g, ushort* l) {
    __builtin_amdgcn_global_load_lds(
        (const __attribute__((address_space(1))) void*)g,
        (__attribute__((address_space(3))) void*)l, 16, 0, 0);
}

// ------------------------------------------------------------- fused prep kernel
// blocks [0,8192): cast X f32->bf16 (float4/thread, 1024 elems/block; 4096*2048 total)
// then 4 transpose+cast jobs (32x32 tiles, 256 thr as 32x8)
#define PREP_CAST   8192
#define PREP_WQ     (PREP_CAST)              // 64x64 tiles
#define PREP_WK     (PREP_WQ + 4096)         // 32x64
#define PREP_WV     (PREP_WK + 2048)
#define PREP_WO     (PREP_WV + 2048)         // 64x64
#define PREP_TOTAL  (PREP_WO + 4096)

__device__ __forceinline__ void tcast_body(
    const float* __restrict__ in, ushort* __restrict__ out,
    int K, int N, int bx, int by, int t)
{
    __shared__ float tile[32][33];
    int n0 = bx * 32, k0 = by * 32;
    int tx = t & 31, ty = t >> 5; // 32 x 8
#pragma unroll
    for (int i = 0; i < 32; i += 8)
        tile[ty + i][tx] = in[(size_t)(k0 + ty + i) * N + n0 + tx];
    __syncthreads();
#pragma unroll
    for (int i = 0; i < 32; i += 8)
        out[(size_t)(n0 + ty + i) * K + k0 + tx] = f2bf(tile[tx][ty + i]);
}

__global__ __launch_bounds__(256) void prep(
    const float* __restrict__ X,  const float* __restrict__ wq,
    const float* __restrict__ wk, const float* __restrict__ wv,
    const float* __restrict__ wo,
    ushort* __restrict__ Xb, ushort* __restrict__ WqkvT, ushort* __restrict__ Wot)
{
    int bid = blockIdx.x, t = threadIdx.x;
    if (bid < PREP_CAST) {
        int i = (bid * 256 + t) * 4;
        float4 v = *(const float4*)&X[i];
        ushort4 o = { f2bf(v.x), f2bf(v.y), f2bf(v.z), f2bf(v.w) };
        *(ushort4*)&Xb[i] = o;
    } else if (bid < PREP_WK) {
        int l = bid - PREP_WQ;
        tcast_body(wq, WqkvT, 2048, 2048, l & 63, l >> 6, t);
    } else if (bid < PREP_WV) {
        int l = bid - PREP_WK;
        tcast_body(wk, WqkvT + (size_t)2048 * 2048, 2048, 1024, l & 31, l >> 5, t);
    } else if (bid < PREP_WO) {
        int l = bid - PREP_WV;
        tcast_body(wv, WqkvT + (size_t)3072 * 2048, 2048, 1024, l & 31, l >> 5, t);
    } else {
        int l = bid - PREP_WO;
        tcast_body(wo, Wot, 2048, 2048, l & 63, l >> 6, t);
    }
}

// ---------------------------------------------------------------- GEMM: C = A @ Bt^T
// m97 structure: 128x128 block, BK=32, unpadded LDS, global_load_lds width-16.
template <typename OutT>
__global__ __launch_bounds__(256) void gemm_bt(
    const ushort* __restrict__ A, const ushort* __restrict__ Bt,
    OutT* __restrict__ C, int M, int N, int K)
{
    __shared__ __align__(16) ushort As[128 * 32];
    __shared__ __align__(16) ushort Bs[128 * 32];
    const int t = threadIdx.x;
    const int lane = t & 63, wave = t >> 6;
    const int quad = lane >> 4, l15 = lane & 15;
    const int m0 = blockIdx.y * 128, n0 = blockIdx.x * 128;
    const int wm = (wave >> 1) * 64, wn = (wave & 1) * 64;

    const f32x4 zv = {0.f, 0.f, 0.f, 0.f};
    f32x4 acc[4][4];
#pragma unroll
    for (int i = 0; i < 4; i++)
#pragma unroll
        for (int j = 0; j < 4; j++) acc[i][j] = zv;

    const int srow = t >> 2, sc8 = (t & 3) << 3;

    for (int k0 = 0; k0 < K; k0 += 32) {
        __syncthreads();
#pragma unroll
        for (int i = 0; i < 2; i++) {
            gll16(&A[(size_t)(m0 + srow + i * 64) * K + k0 + sc8], &As[(i * 256 + t) * 8]);
            gll16(&Bt[(size_t)(n0 + srow + i * 64) * K + k0 + sc8], &Bs[(i * 256 + t) * 8]);
        }
        __syncthreads();
        uint4 af[4], bf[4];
#pragma unroll
        for (int i = 0; i < 4; i++)
            af[i] = *(const uint4*)&As[(wm + i * 16 + l15) * 32 + quad * 8];
#pragma unroll
        for (int i = 0; i < 4; i++)
            bf[i] = *(const uint4*)&Bs[(wn + i * 16 + l15) * 32 + quad * 8];
#pragma unroll
        for (int mi = 0; mi < 4; mi++)
#pragma unroll
            for (int ni = 0; ni < 4; ni++)
                acc[mi][ni] = __builtin_amdgcn_mfma_f32_16x16x32_bf16(
                    as_bf8(af[mi]), as_bf8(bf[ni]), acc[mi][ni], 0, 0, 0);
    }
#pragma unroll
    for (int mi = 0; mi < 4; mi++)
#pragma unroll
        for (int ni = 0; ni < 4; ni++)
#pragma unroll
            for (int r = 0; r < 4; r++) {
                int row = m0 + wm + mi * 16 + quad * 4 + r;
                int col = n0 + wn + ni * 16 + l15;
                store_el(&C[(size_t)row * N + col], acc[mi][ni][r]);
            }
}

// ------------------------------------------- per-head RMSNorm + RoPE, in place on QKV
// One block per (b,s); wave handles 2 heads/pass (lanes 0-31 head A, 32-63 head B),
// u32 accesses, angles hoisted. Heads: pass*8 + wave*2 + hsel. 3 passes cover 24 heads.
__global__ __launch_bounds__(256) void norm_rope(
    ushort* __restrict__ qkv, const float* __restrict__ qw, const float* __restrict__ kw)
{
    int row = blockIdx.x;            // b*S + s
    int s = row & (SS - 1);
    int lane = threadIdx.x & 63, wave = threadIdx.x >> 6;
    int l = lane & 31, hsel = lane >> 5;
    // this lane covers d pairs (2l, 2l+64) and (2l+1, 2l+65)
    float d0 = (float)(2 * l), d1 = d0 + 1.0f;
    float inv0 = expf(-d0 * (1.0f / 64.0f) * 9.210340371976184f);
    float inv1 = expf(-d1 * (1.0f / 64.0f) * 9.210340371976184f);
    float c0, s0, c1, s1;
    sincosf((float)s * inv0, &s0, &c0);
    sincosf((float)s * inv1, &s1, &c1);
    float qw0 = qw[2 * l], qw1 = qw[2 * l + 1], qy0 = qw[2 * l + 64], qy1 = qw[2 * l + 65];
    float kw0 = kw[2 * l], kw1 = kw[2 * l + 1], ky0 = kw[2 * l + 64], ky1 = kw[2 * l + 65];

#pragma unroll
    for (int pass = 0; pass < 3; pass++) {
        int h = pass * 8 + wave * 2 + hsel;
        ushort* p = qkv + (size_t)row * QKVW + h * 128;
        unsigned int ulo = *(const unsigned int*)&p[2 * l];
        unsigned int uhi = *(const unsigned int*)&p[2 * l + 64];
        float x0 = bf2f((ushort)ulo), x1 = bf2f((ushort)(ulo >> 16));
        float y0 = bf2f((ushort)uhi), y1 = bf2f((ushort)(uhi >> 16));
        float ssum = x0 * x0 + x1 * x1 + y0 * y0 + y1 * y1;
#pragma unroll
        for (int xm = 1; xm < 32; xm <<= 1) ssum += __shfl_xor(ssum, xm, 64);
        float r = rsqrtf(ssum * (1.0f / 128.0f) + 1e-6f);
        bool isq = (h < 16);
        float w0 = isq ? qw0 : kw0, w1 = isq ? qw1 : kw1;
        float v0 = isq ? qy0 : ky0, v1 = isq ? qy1 : ky1;
        float sc = isq ? 0.08838834764831845f : 1.0f; // 1/sqrt(128) folded into q
        float nx0 = w0 * (x0 * r), nx1 = w1 * (x1 * r);
        float ny0 = v0 * (y0 * r), ny1 = v1 * (y1 * r);
        float ox0 = (nx0 * c0 - ny0 * s0) * sc, ox1 = (nx1 * c1 - ny1 * s1) * sc;
        float oy0 = (ny0 * c0 + nx0 * s0) * sc, oy1 = (ny1 * c1 + nx1 * s1) * sc;
        *(unsigned int*)&p[2 * l]      = (unsigned int)f2bf(ox0) | ((unsigned int)f2bf(ox1) << 16);
        *(unsigned int*)&p[2 * l + 64] = (unsigned int)f2bf(oy0) | ((unsigned int)f2bf(oy1) << 16);
    }
}

// ---------------------------------------------------------------- flash attention
// Block = (q-tile 128, head, batch); 4 waves, wave w owns q rows w*32..w*32+31.
// SWAPPED QK^T (T12): sc = mfma(K_frag, Q_frag) -> C[m=key][n=q], so each lane
// holds a full P column for its own q-row. P->bf16 A-frags built in-register via
// v_cvt_pk_bf16_f32 + permlane32_swap (no Ps LDS roundtrip). Fixed-max softmax,
// lane-local row-sum. Additive mask pre-expanded to LDS Madd[2048] (broadcast reads).
// K via global_load_lds (xor swizzle via global-side lane permutation); V
// reg-prefetched one tile ahead. LDS: Ks 16K + Vt 16K + Madd 8K = 40 KB.
__global__ __launch_bounds__(256, 2) void flash_attn(
    const ushort* __restrict__ qkv, const float* __restrict__ mask, ushort* __restrict__ O)
{
    __shared__ __align__(16) ushort Ks[64 * 128];   // [key][dchunk ^ (key&15)]
    __shared__ __align__(16) ushort Vt[128 * 64];   // [d][keychunk ^ (d&7)]
    __shared__ __align__(16) float  Madd[SS];       // (1-mask)*-1e30 per key
    const int t = threadIdx.x;
    const int lane = t & 63, wave = t >> 6;
    const int l31 = lane & 31, half = lane >> 5;
    const int b = blockIdx.z, h = blockIdx.y, q0 = blockIdx.x * 128;
    const int kh = h >> 1; // GQA

    // stage additive mask once (covered by the first loop-top barrier)
#pragma unroll
    for (int i = 0; i < 2; i++) {
        int idx = i * 1024 + t * 4;
        float4 mv = *(const float4*)&mask[b * SS + idx];
        float4 o = { (1.f - mv.x) * -1e30f, (1.f - mv.y) * -1e30f,
                     (1.f - mv.z) * -1e30f, (1.f - mv.w) * -1e30f };
        *(float4*)&Madd[idx] = o;
    }

    // Q frags for 32x32x16: lane holds Q[row=wave*32+l31][d=kt*16+half*8+j]
    uint4 aq[8];
    {
        const ushort* qp = qkv + ((size_t)(b * SS + q0 + wave * 32 + l31)) * QKVW + h * 128 + half * 8;
#pragma unroll
        for (int kt = 0; kt < 8; kt++) aq[kt] = *(const uint4*)&qp[kt * 16];
    }
    f32x16 acc_o[4];
#pragma unroll
    for (int i = 0; i < 4; i++)
#pragma unroll
        for (int r = 0; r < 16; r++) acc_o[i][r] = 0.f;
    float lp[4] = {0.f, 0.f, 0.f, 0.f}; // lane-local row-sum partials (q = l31)

    const ushort* Kg = qkv + (size_t)b * SS * QKVW + 2048 + kh * 128;
    const ushort* Vg = qkv + (size_t)b * SS * QKVW + 3072 + kh * 128;

    const int vp = t & 31, vdc = t >> 5; // V staging: key pair (2vp,2vp+1), d groups
    uint4 vreg[4];
#define LOAD_V(K0)                                                                  \
    {                                                                               \
        _Pragma("unroll")                                                           \
        for (int pass = 0; pass < 2; pass++) {                                      \
            int d0 = (vdc + pass * 8) * 8;                                          \
            vreg[pass * 2 + 0] = *(const uint4*)&Vg[(size_t)((K0) + 2 * vp) * QKVW + d0];     \
            vreg[pass * 2 + 1] = *(const uint4*)&Vg[(size_t)((K0) + 2 * vp + 1) * QKVW + d0]; \
        }                                                                           \
    }
    LOAD_V(0);

    for (int k0 = 0; k0 < SS; k0 += 64) {
        __syncthreads(); // prior tile's LDS reads done
        // K tile: async global->LDS; physical slot (row,cp) holds logical chunk cp^(row&15)
#pragma unroll
        for (int i = 0; i < 4; i++) {
            int chunk = i * 256 + t;
            int row = chunk >> 4, cp = chunk & 15;
            int cl = cp ^ (row & 15);
            gll16(&Kg[(size_t)(k0 + row) * QKVW + cl * 8], &Ks[chunk * 8]);
        }
        // V tile: transpose from vreg; slot for key-chunk c=(vp>>2) is c^(d&7)
#pragma unroll
        for (int pass = 0; pass < 2; pass++) {
            const ushort* pa_ = (const ushort*)&vreg[pass * 2 + 0];
            const ushort* pb_ = (const ushort*)&vreg[pass * 2 + 1];
            int d0 = (vdc + pass * 8) * 8;
#pragma unroll
            for (int j = 0; j < 8; j++) {
                int cp = (vp >> 2) ^ j;
                unsigned int v = (unsigned int)pa_[j] | ((unsigned int)pb_[j] << 16);
                *(unsigned int*)&Vt[(d0 + j) * 64 + cp * 8 + (vp & 3) * 2] = v;
            }
        }
        __syncthreads(); // drains vmcnt: Ks ready
        if (k0 + 64 < SS) LOAD_V(k0 + 64);

        // scores (swapped): S^T = K Q^T, C[m=key][n=q]; 2 key-groups of 32
        f32x16 sc[2];
        __builtin_amdgcn_s_setprio(1);
#pragma unroll
        for (int nt = 0; nt < 2; nt++) {
#pragma unroll
            for (int r = 0; r < 16; r++) sc[nt][r] = 0.f;
#pragma unroll
            for (int kt = 0; kt < 8; kt++) {
                int cp = (kt * 2 + half) ^ (l31 & 15);
                uint4 bk = *(const uint4*)&Ks[(nt * 32 + l31) * 128 + cp * 8];
                sc[nt] = __builtin_amdgcn_mfma_f32_32x32x16_bf16(
                    as_bf8(bk), as_bf8(aq[kt]), sc[nt], 0, 0, 0);
            }
        }
        __builtin_amdgcn_s_setprio(0);

        // mask + exp + lane-local row sums; key = k0 + nt*32 + (r&3)+8*(r>>2)+4*half
        // then pack P into PV A-frags fully in-register (cvt_pk + permlane32_swap)
        uint4 pa[4];
#pragma unroll
        for (int nt = 0; nt < 2; nt++) {
            float p[16];
#pragma unroll
            for (int g = 0; g < 4; g++) {
                f32x4 em = *(const f32x4*)&Madd[k0 + nt * 32 + 4 * half + g * 8];
#pragma unroll
                for (int j = 0; j < 4; j++) {
                    int r = g * 4 + j;
                    float pv = __expf(sc[nt][r] + em[j]);
                    p[r] = pv;
                    lp[j] += pv;
                }
            }
            unsigned int pk[8];
#pragma unroll
            for (int i = 0; i < 8; i++) pk[i] = cvtpk_bf16(p[2 * i], p[2 * i + 1]);
            // exchange key-halves across the lane<32/lane>=32 split
            auto sA = __builtin_amdgcn_permlane32_swap(pk[0], pk[2], false, false);
            auto sB = __builtin_amdgcn_permlane32_swap(pk[1], pk[3], false, false);
            auto sC = __builtin_amdgcn_permlane32_swap(pk[4], pk[6], false, false);
            auto sD = __builtin_amdgcn_permlane32_swap(pk[5], pk[7], false, false);
            uint4 f0, f1;
            f0.x = sA[0]; f0.y = sB[0]; f0.z = sA[1]; f0.w = sB[1];
            f1.x = sC[0]; f1.y = sD[0]; f1.z = sC[1]; f1.w = sD[1];
            pa[nt * 2 + 0] = f0;
            pa[nt * 2 + 1] = f1;
        }

        // PV: A = P[32 q x 64 keys] (in-register), B = Vt[keys x d], 4 k-steps, 4 d-tiles
        __builtin_amdgcn_s_setprio(1);
#pragma unroll
        for (int kt2 = 0; kt2 < 4; kt2++) {
            int kc = kt2 * 2 + half;
            int co = (kc ^ (l31 & 7)) * 8;
#pragma unroll
            for (int nt = 0; nt < 4; nt++) {
                uint4 bv = *(const uint4*)&Vt[(nt * 32 + l31) * 64 + co];
                acc_o[nt] = __builtin_amdgcn_mfma_f32_32x32x16_bf16(
                    as_bf8(pa[kt2]), as_bf8(bv), acc_o[nt], 0, 0, 0);
            }
        }
        __builtin_amdgcn_s_setprio(0);
    }
    // row-sum: lane already holds full sum for q=l31 over its half's keys;
    // combine the two halves, then broadcast to epilogue row layout
    float lsum = (lp[0] + lp[1]) + (lp[2] + lp[3]);
    lsum += __shfl_xor(lsum, 32, 64);
    float linv = 1.0f / lsum;
    float li[16];
#pragma unroll
    for (int r = 0; r < 16; r++)
        li[r] = __shfl(linv, (r & 3) + 8 * (r >> 2) + 4 * half, 64);
    // epilogue
#pragma unroll
    for (int nt = 0; nt < 4; nt++)
#pragma unroll
        for (int r = 0; r < 16; r++) {
            int prow = (r & 3) + 8 * (r >> 2) + 4 * half;
            int qrow = q0 + wave * 32 + prow;
            int d = nt * 32 + l31;
            float v = acc_o[nt][r] * li[r];
            O[((size_t)(b * SS + qrow)) * (NHQ * DD) + h * 128 + d] = f2bf(v);
        }
}

// ---------------------------------------------------------------- launch
extern "C" void kernel_launch(void* const* d_in, const int* in_sizes, int n_in,
                              void* d_out, int out_size, void* d_ws, size_t ws_size,
                              hipStream_t stream)
{
    const float* X    = (const float*)d_in[0];
    const float* mask = (const float*)d_in[1];
    const float* wq   = (const float*)d_in[2];
    const float* wk   = (const float*)d_in[3];
    const float* wv   = (const float*)d_in[4];
    const float* wo   = (const float*)d_in[5];
    const float* qnw  = (const float*)d_in[6];
    const float* knw  = (const float*)d_in[7];
    float* out = (float*)d_out;

    const size_t M = (size_t)BB * SS; // 4096
    ushort* Xb    = (ushort*)d_ws;                       // 4096x2048
    ushort* WqkvT = Xb    + M * HID;                     // 4096x2048 (Wq^T|Wk^T|Wv^T rows)
    ushort* Wot   = WqkvT + (size_t)4096 * HID;          // 2048x2048
    ushort* QKV   = Wot   + (size_t)2048 * 2048;         // 4096x4096
    ushort* Obuf  = QKV   + M * QKVW;                    // 4096x2048

    prep<<<PREP_TOTAL, 256, 0, stream>>>(X, wq, wk, wv, wo, Xb, WqkvT, Wot);

    // fused QKV projection: (4096,2048) @ (4096,2048)^T -> (4096,4096)
    gemm_bt<ushort><<<dim3(4096 / 128, 4096 / 128), 256, 0, stream>>>(Xb, WqkvT, QKV, 4096, 4096, 2048);

    norm_rope<<<(int)M, 256, 0, stream>>>(QKV, qnw, knw);

    flash_attn<<<dim3(SS / 128, NHQ, BB), 256, 0, stream>>>(QKV, mask, Obuf);

    // out projection: (4096,2048) @ (2048,2048)^T -> fp32 d_out
    gemm_bt<float><<<dim3(2048 / 128, 4096 / 128), 256, 0, stream>>>(Obuf, Wot, out, 4096, 2048, 2048);
}

// Round 2
// 352.266 us; speedup vs baseline: 1.2324x; 1.1194x over previous
//
#include <hip/hip_runtime.h>
#include <stdint.h>

// Problem constants
#define BB   2
#define SS   2048
#define HID  2048
#define NHQ  16
#define NKV  8
#define DD   128
// QKV fused row layout: [q: 16*128 | k: 8*128 | v: 8*128] = 4096 bf16 per (b,s)
#define QKVW 4096

typedef __bf16 v8bf   __attribute__((ext_vector_type(8)));
typedef float  f32x4  __attribute__((ext_vector_type(4)));
typedef float  f32x16 __attribute__((ext_vector_type(16)));

__device__ __forceinline__ float bf2f(ushort u) {
    union { unsigned int i; float f; } x; x.i = ((unsigned int)u) << 16; return x.f;
}
__device__ __forceinline__ ushort f2bf(float f) {
    union { float f; unsigned int i; } x; x.f = f;
    unsigned int i = x.i;
    return (ushort)((i + 0x7fffu + ((i >> 16) & 1u)) >> 16); // RNE, finite inputs
}
__device__ __forceinline__ v8bf as_bf8(uint4 u) { return __builtin_bit_cast(v8bf, u); }

__device__ __forceinline__ unsigned int cvtpk_bf16(float lo, float hi) {
    unsigned int r;
    asm("v_cvt_pk_bf16_f32 %0, %1, %2" : "=v"(r) : "v"(lo), "v"(hi));
    return r;
}

__device__ __forceinline__ void store_el(float* p, float v)  { *p = v; }
__device__ __forceinline__ void store_el(ushort* p, float v) { *p = f2bf(v); }

// async global->LDS, 16B per lane; lds must be wave-uniform-base + lane*16
__device__ __forceinline__ void gll16(const ushort* g, ushort* l) {
    __builtin_amdgcn_global_load_lds(
        (const __attribute__((address_space(1))) void*)g,
        (__attribute__((address_space(3))) void*)l, 16, 0, 0);
}

// st_16x32 swizzle: physical byte = logical byte ^ ((bit9)<<5). For a row-major
// [R][64] bf16 tile (row stride 128B), bit9 of the logical byte = (row>>2)&1.
// Returns ELEMENT offset for logical (row, lcol_bytes).
__device__ __forceinline__ int swz_off(int r, int lcolb) {
    return r * 64 + (((lcolb) ^ ((r & 4) << 3)) >> 1);
}

// ------------------------------------------------------------- fused prep kernel
#define PREP_CAST   8192
#define PREP_WQ     (PREP_CAST)              // 64x64 tiles
#define PREP_WK     (PREP_WQ + 4096)         // 32x64
#define PREP_WV     (PREP_WK + 2048)
#define PREP_WO     (PREP_WV + 2048)         // 64x64
#define PREP_TOTAL  (PREP_WO + 4096)

__device__ __forceinline__ void tcast_body(
    const float* __restrict__ in, ushort* __restrict__ out,
    int K, int N, int bx, int by, int t)
{
    __shared__ float tile[32][33];
    int n0 = bx * 32, k0 = by * 32;
    int tx = t & 31, ty = t >> 5; // 32 x 8
#pragma unroll
    for (int i = 0; i < 32; i += 8)
        tile[ty + i][tx] = in[(size_t)(k0 + ty + i) * N + n0 + tx];
    __syncthreads();
#pragma unroll
    for (int i = 0; i < 32; i += 8)
        out[(size_t)(n0 + ty + i) * K + k0 + tx] = f2bf(tile[tx][ty + i]);
}

__global__ __launch_bounds__(256) void prep(
    const float* __restrict__ X,  const float* __restrict__ wq,
    const float* __restrict__ wk, const float* __restrict__ wv,
    const float* __restrict__ wo,
    ushort* __restrict__ Xb, ushort* __restrict__ WqkvT, ushort* __restrict__ Wot)
{
    int bid = blockIdx.x, t = threadIdx.x;
    if (bid < PREP_CAST) {
        int i = (bid * 256 + t) * 4;
        float4 v = *(const float4*)&X[i];
        ushort4 o = { f2bf(v.x), f2bf(v.y), f2bf(v.z), f2bf(v.w) };
        *(ushort4*)&Xb[i] = o;
    } else if (bid < PREP_WK) {
        int l = bid - PREP_WQ;
        tcast_body(wq, WqkvT, 2048, 2048, l & 63, l >> 6, t);
    } else if (bid < PREP_WV) {
        int l = bid - PREP_WK;
        tcast_body(wk, WqkvT + (size_t)2048 * 2048, 2048, 1024, l & 31, l >> 5, t);
    } else if (bid < PREP_WO) {
        int l = bid - PREP_WV;
        tcast_body(wv, WqkvT + (size_t)3072 * 2048, 2048, 1024, l & 31, l >> 5, t);
    } else {
        int l = bid - PREP_WO;
        tcast_body(wo, Wot, 2048, 2048, l & 63, l >> 6, t);
    }
}

// ---------------------------------------------------------------- GEMM: C = A @ Bt^T
// Phased-pipeline structure (T2+T3+T4+T5): BM=256, BN=128, BK=64, 8 waves (512 thr),
// ring-of-3 LDS K-tile buffers (144 KB). Tile T computes from ring[T%3] while tile
// T+2 stages into ring[(T+2)%3] (slot of T-1, whose reads completed a full tile ago
// -> no overwrite-while-read hazard). Per tile: 2 phases (n-half quadrants), each
// {ds_read frags || 3x global_load_lds || s_barrier || lgkmcnt(0) || 16 MFMA}.
// vmcnt(6) once per tile (counted, never 0 until 2-tile epilogue drain).
// LDS tiles st_16x32-swizzled; staging uses inverse-swizzled global source.
template <typename OutT>
__global__ __launch_bounds__(512, 2) void gemm_bt2(
    const ushort* __restrict__ A, const ushort* __restrict__ Bt,
    OutT* __restrict__ C, int M, int N, int K)
{
    __shared__ __align__(16) ushort As[3][256 * 64];
    __shared__ __align__(16) ushort Bs[3][128 * 64];
    const int t = threadIdx.x;
    const int lane = t & 63, wave = t >> 6;
    const int quad = lane >> 4, l15 = lane & 15;
    const int m0 = blockIdx.y * 256, n0 = blockIdx.x * 128;
    const int wm = (wave >> 1) * 64;  // wave A-row base within 256
    const int wn = (wave & 1) * 64;   // wave B-row base within 128

    const f32x4 zv = {0.f, 0.f, 0.f, 0.f};
    f32x4 acc[4][4]; // [mf][nf], nf 0..1 phase0, 2..3 phase1
#pragma unroll
    for (int i = 0; i < 4; i++)
#pragma unroll
        for (int j = 0; j < 4; j++) acc[i][j] = zv;

    // staging source coords: physical 16B chunk (j*512+t) holds logical chunk
    // l = p ^ ((p>>9&1)<<5); logical -> (row, col)
    int arow[4], acol[4];
#pragma unroll
    for (int j = 0; j < 4; j++) {
        int p = (j * 512 + t) * 16;
        int l = p ^ (((p >> 9) & 1) << 5);
        arow[j] = l >> 7; acol[j] = (l & 127) >> 1;
    }
    int brow[2], bcol[2];
#pragma unroll
    for (int j = 0; j < 2; j++) {
        int p = (j * 512 + t) * 16;
        int l = p ^ (((p >> 9) & 1) << 5);
        brow[j] = l >> 7; bcol[j] = (l & 127) >> 1;
    }

    // fragment LDS element offsets (swizzled)
    int aoff[4][2], boff[2][2][2];
#pragma unroll
    for (int mf = 0; mf < 4; mf++)
#pragma unroll
        for (int kk = 0; kk < 2; kk++)
            aoff[mf][kk] = swz_off(wm + mf * 16 + l15, kk * 64 + quad * 16);
#pragma unroll
    for (int q = 0; q < 2; q++)
#pragma unroll
        for (int nf = 0; nf < 2; nf++)
#pragma unroll
            for (int kk = 0; kk < 2; kk++)
                boff[q][nf][kk] = swz_off(wn + q * 32 + nf * 16 + l15, kk * 64 + quad * 16);

#define STAGE_A(j, slot, kk0) \
    gll16(&A[(size_t)(m0 + arow[j]) * K + (kk0) + acol[j]], &As[slot][0] + ((j) * 512 + t) * 8)
#define STAGE_B(j, slot, kk0) \
    gll16(&Bt[(size_t)(n0 + brow[j]) * K + (kk0) + bcol[j]], &Bs[slot][0] + ((j) * 512 + t) * 8)

    const int NT = K >> 6;

    // prologue: stage tiles 0 and 1, wait tile 0
#pragma unroll
    for (int j = 0; j < 4; j++) STAGE_A(j, 0, 0);
#pragma unroll
    for (int j = 0; j < 2; j++) STAGE_B(j, 0, 0);
#pragma unroll
    for (int j = 0; j < 4; j++) STAGE_A(j, 1, 64);
#pragma unroll
    for (int j = 0; j < 2; j++) STAGE_B(j, 1, 64);
    asm volatile("s_waitcnt vmcnt(6)" ::: "memory");
    __builtin_amdgcn_s_barrier();

    int cur = 0;
    for (int T = 0; T < NT; T++) {
        const ushort* Ac = &As[cur][0];
        const ushort* Bc = &Bs[cur][0];
        int stg = cur + 2; if (stg >= 3) stg -= 3;
        const int k2 = (T + 2) << 6;
        const bool do_stage = (T + 2) < NT;

        // ---------- phase 0: read all A-frags + B q=0; stage 3; MFMA n-half 0
        uint4 af[4][2], bf[2][2];
#pragma unroll
        for (int mf = 0; mf < 4; mf++)
#pragma unroll
            for (int kk = 0; kk < 2; kk++)
                af[mf][kk] = *(const uint4*)&Ac[aoff[mf][kk]];
#pragma unroll
        for (int nf = 0; nf < 2; nf++)
#pragma unroll
            for (int kk = 0; kk < 2; kk++)
                bf[nf][kk] = *(const uint4*)&Bc[boff[0][nf][kk]];
        if (do_stage) {
            STAGE_A(0, stg, k2); STAGE_A(1, stg, k2); STAGE_B(0, stg, k2);
        }
        __builtin_amdgcn_s_barrier();
        asm volatile("s_waitcnt lgkmcnt(0)" ::: "memory");
        __builtin_amdgcn_sched_barrier(0);
        __builtin_amdgcn_s_setprio(1);
#pragma unroll
        for (int mf = 0; mf < 4; mf++)
#pragma unroll
            for (int nf = 0; nf < 2; nf++)
#pragma unroll
                for (int kk = 0; kk < 2; kk++)
                    acc[mf][nf] = __builtin_amdgcn_mfma_f32_16x16x32_bf16(
                        as_bf8(af[mf][kk]), as_bf8(bf[nf][kk]), acc[mf][nf], 0, 0, 0);
        __builtin_amdgcn_s_setprio(0);
        __builtin_amdgcn_s_barrier();

        // ---------- phase 1: read B q=1; stage 3; counted vmcnt; MFMA n-half 1
#pragma unroll
        for (int nf = 0; nf < 2; nf++)
#pragma unroll
            for (int kk = 0; kk < 2; kk++)
                bf[nf][kk] = *(const uint4*)&Bc[boff[1][nf][kk]];
        if (do_stage) {
            STAGE_A(2, stg, k2); STAGE_A(3, stg, k2); STAGE_B(1, stg, k2);
            asm volatile("s_waitcnt vmcnt(6)" ::: "memory"); // tile T+1 landed
        } else if (T + 2 == NT) {
            asm volatile("s_waitcnt vmcnt(0)" ::: "memory"); // epilogue drain
        }
        __builtin_amdgcn_s_barrier();
        asm volatile("s_waitcnt lgkmcnt(0)" ::: "memory");
        __builtin_amdgcn_sched_barrier(0);
        __builtin_amdgcn_s_setprio(1);
#pragma unroll
        for (int mf = 0; mf < 4; mf++)
#pragma unroll
            for (int nf = 0; nf < 2; nf++)
#pragma unroll
                for (int kk = 0; kk < 2; kk++)
                    acc[mf][2 + nf] = __builtin_amdgcn_mfma_f32_16x16x32_bf16(
                        as_bf8(af[mf][kk]), as_bf8(bf[nf][kk]), acc[mf][2 + nf], 0, 0, 0);
        __builtin_amdgcn_s_setprio(0);
        __builtin_amdgcn_s_barrier();

        cur++; if (cur == 3) cur = 0;
    }
#undef STAGE_A
#undef STAGE_B

    // epilogue: C[m0+wm+mf*16+quad*4+r][n0+wn+nf*16+l15]
#pragma unroll
    for (int mf = 0; mf < 4; mf++)
#pragma unroll
        for (int nf = 0; nf < 4; nf++)
#pragma unroll
            for (int r = 0; r < 4; r++) {
                int row = m0 + wm + mf * 16 + quad * 4 + r;
                int col = n0 + wn + nf * 16 + l15;
                store_el(&C[(size_t)row * N + col], acc[mf][nf][r]);
            }
}

// ------------------------------------------- per-head RMSNorm + RoPE, in place on QKV
__global__ __launch_bounds__(256) void norm_rope(
    ushort* __restrict__ qkv, const float* __restrict__ qw, const float* __restrict__ kw)
{
    int row = blockIdx.x;            // b*S + s
    int s = row & (SS - 1);
    int lane = threadIdx.x & 63, wave = threadIdx.x >> 6;
    int l = lane & 31, hsel = lane >> 5;
    float d0 = (float)(2 * l), d1 = d0 + 1.0f;
    float inv0 = expf(-d0 * (1.0f / 64.0f) * 9.210340371976184f);
    float inv1 = expf(-d1 * (1.0f / 64.0f) * 9.210340371976184f);
    float c0, s0, c1, s1;
    sincosf((float)s * inv0, &s0, &c0);
    sincosf((float)s * inv1, &s1, &c1);
    float qw0 = qw[2 * l], qw1 = qw[2 * l + 1], qy0 = qw[2 * l + 64], qy1 = qw[2 * l + 65];
    float kw0 = kw[2 * l], kw1 = kw[2 * l + 1], ky0 = kw[2 * l + 64], ky1 = kw[2 * l + 65];

#pragma unroll
    for (int pass = 0; pass < 3; pass++) {
        int h = pass * 8 + wave * 2 + hsel;
        ushort* p = qkv + (size_t)row * QKVW + h * 128;
        unsigned int ulo = *(const unsigned int*)&p[2 * l];
        unsigned int uhi = *(const unsigned int*)&p[2 * l + 64];
        float x0 = bf2f((ushort)ulo), x1 = bf2f((ushort)(ulo >> 16));
        float y0 = bf2f((ushort)uhi), y1 = bf2f((ushort)(uhi >> 16));
        float ssum = x0 * x0 + x1 * x1 + y0 * y0 + y1 * y1;
#pragma unroll
        for (int xm = 1; xm < 32; xm <<= 1) ssum += __shfl_xor(ssum, xm, 64);
        float r = rsqrtf(ssum * (1.0f / 128.0f) + 1e-6f);
        bool isq = (h < 16);
        float w0 = isq ? qw0 : kw0, w1 = isq ? qw1 : kw1;
        float v0 = isq ? qy0 : ky0, v1 = isq ? qy1 : ky1;
        float sc = isq ? 0.08838834764831845f : 1.0f; // 1/sqrt(128) folded into q
        float nx0 = w0 * (x0 * r), nx1 = w1 * (x1 * r);
        float ny0 = v0 * (y0 * r), ny1 = v1 * (y1 * r);
        float ox0 = (nx0 * c0 - ny0 * s0) * sc, ox1 = (nx1 * c1 - ny1 * s1) * sc;
        float oy0 = (ny0 * c0 + nx0 * s0) * sc, oy1 = (ny1 * c1 + nx1 * s1) * sc;
        *(unsigned int*)&p[2 * l]      = (unsigned int)f2bf(ox0) | ((unsigned int)f2bf(ox1) << 16);
        *(unsigned int*)&p[2 * l + 64] = (unsigned int)f2bf(oy0) | ((unsigned int)f2bf(oy1) << 16);
    }
}

// ---------------------------------------------------------------- flash attention
// Swapped QK^T (T12): in-register P via cvt_pk + permlane32_swap; no Ps LDS.
__global__ __launch_bounds__(256, 2) void flash_attn(
    const ushort* __restrict__ qkv, const float* __restrict__ mask, ushort* __restrict__ O)
{
    __shared__ __align__(16) ushort Ks[64 * 128];   // [key][dchunk ^ (key&15)]
    __shared__ __align__(16) ushort Vt[128 * 64];   // [d][keychunk ^ (d&7)]
    __shared__ __align__(16) float  Madd[SS];       // (1-mask)*-1e30 per key
    const int t = threadIdx.x;
    const int lane = t & 63, wave = t >> 6;
    const int l31 = lane & 31, half = lane >> 5;
    const int b = blockIdx.z, h = blockIdx.y, q0 = blockIdx.x * 128;
    const int kh = h >> 1; // GQA

#pragma unroll
    for (int i = 0; i < 2; i++) {
        int idx = i * 1024 + t * 4;
        float4 mv = *(const float4*)&mask[b * SS + idx];
        float4 o = { (1.f - mv.x) * -1e30f, (1.f - mv.y) * -1e30f,
                     (1.f - mv.z) * -1e30f, (1.f - mv.w) * -1e30f };
        *(float4*)&Madd[idx] = o;
    }

    uint4 aq[8];
    {
        const ushort* qp = qkv + ((size_t)(b * SS + q0 + wave * 32 + l31)) * QKVW + h * 128 + half * 8;
#pragma unroll
        for (int kt = 0; kt < 8; kt++) aq[kt] = *(const uint4*)&qp[kt * 16];
    }
    f32x16 acc_o[4];
#pragma unroll
    for (int i = 0; i < 4; i++)
#pragma unroll
        for (int r = 0; r < 16; r++) acc_o[i][r] = 0.f;
    float lp[4] = {0.f, 0.f, 0.f, 0.f};

    const ushort* Kg = qkv + (size_t)b * SS * QKVW + 2048 + kh * 128;
    const ushort* Vg = qkv + (size_t)b * SS * QKVW + 3072 + kh * 128;

    const int vp = t & 31, vdc = t >> 5;
    uint4 vreg[4];
#define LOAD_V(K0)                                                                  \
    {                                                                               \
        _Pragma("unroll")                                                           \
        for (int pass = 0; pass < 2; pass++) {                                      \
            int d0 = (vdc + pass * 8) * 8;                                          \
            vreg[pass * 2 + 0] = *(const uint4*)&Vg[(size_t)((K0) + 2 * vp) * QKVW + d0];     \
            vreg[pass * 2 + 1] = *(const uint4*)&Vg[(size_t)((K0) + 2 * vp + 1) * QKVW + d0]; \
        }                                                                           \
    }
    LOAD_V(0);

    for (int k0 = 0; k0 < SS; k0 += 64) {
        __syncthreads();
#pragma unroll
        for (int i = 0; i < 4; i++) {
            int chunk = i * 256 + t;
            int row = chunk >> 4, cp = chunk & 15;
            int cl = cp ^ (row & 15);
            gll16(&Kg[(size_t)(k0 + row) * QKVW + cl * 8], &Ks[chunk * 8]);
        }
#pragma unroll
        for (int pass = 0; pass < 2; pass++) {
            const ushort* pa_ = (const ushort*)&vreg[pass * 2 + 0];
            const ushort* pb_ = (const ushort*)&vreg[pass * 2 + 1];
            int d0 = (vdc + pass * 8) * 8;
#pragma unroll
            for (int j = 0; j < 8; j++) {
                int cp = (vp >> 2) ^ j;
                unsigned int v = (unsigned int)pa_[j] | ((unsigned int)pb_[j] << 16);
                *(unsigned int*)&Vt[(d0 + j) * 64 + cp * 8 + (vp & 3) * 2] = v;
            }
        }
        __syncthreads();
        if (k0 + 64 < SS) LOAD_V(k0 + 64);

        f32x16 sc[2];
        __builtin_amdgcn_s_setprio(1);
#pragma unroll
        for (int nt = 0; nt < 2; nt++) {
#pragma unroll
            for (int r = 0; r < 16; r++) sc[nt][r] = 0.f;
#pragma unroll
            for (int kt = 0; kt < 8; kt++) {
                int cp = (kt * 2 + half) ^ (l31 & 15);
                uint4 bk = *(const uint4*)&Ks[(nt * 32 + l31) * 128 + cp * 8];
                sc[nt] = __builtin_amdgcn_mfma_f32_32x32x16_bf16(
                    as_bf8(bk), as_bf8(aq[kt]), sc[nt], 0, 0, 0);
            }
        }
        __builtin_amdgcn_s_setprio(0);

        uint4 pa[4];
#pragma unroll
        for (int nt = 0; nt < 2; nt++) {
            float p[16];
#pragma unroll
            for (int g = 0; g < 4; g++) {
                f32x4 em = *(const f32x4*)&Madd[k0 + nt * 32 + 4 * half + g * 8];
#pragma unroll
                for (int j = 0; j < 4; j++) {
                    int r = g * 4 + j;
                    float pv = __expf(sc[nt][r] + em[j]);
                    p[r] = pv;
                    lp[j] += pv;
                }
            }
            unsigned int pk[8];
#pragma unroll
            for (int i = 0; i < 8; i++) pk[i] = cvtpk_bf16(p[2 * i], p[2 * i + 1]);
            auto sA = __builtin_amdgcn_permlane32_swap(pk[0], pk[2], false, false);
            auto sB = __builtin_amdgcn_permlane32_swap(pk[1], pk[3], false, false);
            auto sC = __builtin_amdgcn_permlane32_swap(pk[4], pk[6], false, false);
            auto sD = __builtin_amdgcn_permlane32_swap(pk[5], pk[7], false, false);
            uint4 f0, f1;
            f0.x = sA[0]; f0.y = sB[0]; f0.z = sA[1]; f0.w = sB[1];
            f1.x = sC[0]; f1.y = sD[0]; f1.z = sC[1]; f1.w = sD[1];
            pa[nt * 2 + 0] = f0;
            pa[nt * 2 + 1] = f1;
        }

        __builtin_amdgcn_s_setprio(1);
#pragma unroll
        for (int kt2 = 0; kt2 < 4; kt2++) {
            int kc = kt2 * 2 + half;
            int co = (kc ^ (l31 & 7)) * 8;
#pragma unroll
            for (int nt = 0; nt < 4; nt++) {
                uint4 bv = *(const uint4*)&Vt[(nt * 32 + l31) * 64 + co];
                acc_o[nt] = __builtin_amdgcn_mfma_f32_32x32x16_bf16(
                    as_bf8(pa[kt2]), as_bf8(bv), acc_o[nt], 0, 0, 0);
            }
        }
        __builtin_amdgcn_s_setprio(0);
    }
    float lsum = (lp[0] + lp[1]) + (lp[2] + lp[3]);
    lsum += __shfl_xor(lsum, 32, 64);
    float linv = 1.0f / lsum;
    float li[16];
#pragma unroll
    for (int r = 0; r < 16; r++)
        li[r] = __shfl(linv, (r & 3) + 8 * (r >> 2) + 4 * half, 64);
#pragma unroll
    for (int nt = 0; nt < 4; nt++)
#pragma unroll
        for (int r = 0; r < 16; r++) {
            int prow = (r & 3) + 8 * (r >> 2) + 4 * half;
            int qrow = q0 + wave * 32 + prow;
            int d = nt * 32 + l31;
            float v = acc_o[nt][r] * li[r];
            O[((size_t)(b * SS + qrow)) * (NHQ * DD) + h * 128 + d] = f2bf(v);
        }
}

// ---------------------------------------------------------------- launch
extern "C" void kernel_launch(void* const* d_in, const int* in_sizes, int n_in,
                              void* d_out, int out_size, void* d_ws, size_t ws_size,
                              hipStream_t stream)
{
    const float* X    = (const float*)d_in[0];
    const float* mask = (const float*)d_in[1];
    const float* wq   = (const float*)d_in[2];
    const float* wk   = (const float*)d_in[3];
    const float* wv   = (const float*)d_in[4];
    const float* wo   = (const float*)d_in[5];
    const float* qnw  = (const float*)d_in[6];
    const float* knw  = (const float*)d_in[7];
    float* out = (float*)d_out;

    const size_t M = (size_t)BB * SS; // 4096
    ushort* Xb    = (ushort*)d_ws;                       // 4096x2048
    ushort* WqkvT = Xb    + M * HID;                     // 4096x2048 (Wq^T|Wk^T|Wv^T rows)
    ushort* Wot   = WqkvT + (size_t)4096 * HID;          // 2048x2048
    ushort* QKV   = Wot   + (size_t)2048 * 2048;         // 4096x4096
    ushort* Obuf  = QKV   + M * QKVW;                    // 4096x2048

    prep<<<PREP_TOTAL, 256, 0, stream>>>(X, wq, wk, wv, wo, Xb, WqkvT, Wot);

    // fused QKV projection: (4096,2048) @ (4096,2048)^T -> (4096,4096)
    gemm_bt2<ushort><<<dim3(4096 / 128, 4096 / 256), 512, 0, stream>>>(Xb, WqkvT, QKV, 4096, 4096, 2048);

    norm_rope<<<(int)M, 256, 0, stream>>>(QKV, qnw, knw);

    flash_attn<<<dim3(SS / 128, NHQ, BB), 256, 0, stream>>>(QKV, mask, Obuf);

    // out projection: (4096,2048) @ (2048,2048)^T -> fp32 d_out
    gemm_bt2<float><<<dim3(2048 / 128, 4096 / 256), 512, 0, stream>>>(Obuf, Wot, out, 4096, 2048, 2048);
}

// Round 3
// 345.008 us; speedup vs baseline: 1.2583x; 1.0210x over previous
//
#include <hip/hip_runtime.h>
#include <stdint.h>

// Problem constants
#define BB   2
#define SS   2048
#define HID  2048
#define NHQ  16
#define NKV  8
#define DD   128
// QKV fused row layout: [q: 16*128 | k: 8*128 | v: 8*128] = 4096 bf16 per (b,s)
#define QKVW 4096

typedef __bf16 v8bf   __attribute__((ext_vector_type(8)));
typedef float  f32x4  __attribute__((ext_vector_type(4)));
typedef float  f32x16 __attribute__((ext_vector_type(16)));

__device__ __forceinline__ float bf2f(ushort u) {
    union { unsigned int i; float f; } x; x.i = ((unsigned int)u) << 16; return x.f;
}
__device__ __forceinline__ ushort f2bf(float f) {
    union { float f; unsigned int i; } x; x.f = f;
    unsigned int i = x.i;
    return (ushort)((i + 0x7fffu + ((i >> 16) & 1u)) >> 16); // RNE, finite inputs
}
__device__ __forceinline__ v8bf as_bf8(uint4 u) { return __builtin_bit_cast(v8bf, u); }

__device__ __forceinline__ unsigned int cvtpk_bf16(float lo, float hi) {
    unsigned int r;
    asm("v_cvt_pk_bf16_f32 %0, %1, %2" : "=v"(r) : "v"(lo), "v"(hi));
    return r;
}

__device__ __forceinline__ void store_el(float* p, float v)  { *p = v; }
__device__ __forceinline__ void store_el(ushort* p, float v) { *p = f2bf(v); }

// async global->LDS, 16B per lane; lds must be wave-uniform-base + lane*16
__device__ __forceinline__ void gll16(const ushort* g, ushort* l) {
    __builtin_amdgcn_global_load_lds(
        (const __attribute__((address_space(1))) void*)g,
        (__attribute__((address_space(3))) void*)l, 16, 0, 0);
}

// st_16x32 swizzle: physical byte = logical byte ^ ((bit9)<<5). For a row-major
// [R][64] bf16 tile (row stride 128B), bit9 of the logical byte = (row>>2)&1.
// Returns ELEMENT offset for logical (row, lcol_bytes).
__device__ __forceinline__ int swz_off(int r, int lcolb) {
    return r * 64 + (((lcolb) ^ ((r & 4) << 3)) >> 1);
}

// ------------------------------------------------------------- fused prep kernel
#define PREP_CAST   8192
#define PREP_WQ     (PREP_CAST)              // 64x64 tiles
#define PREP_WK     (PREP_WQ + 4096)         // 32x64
#define PREP_WV     (PREP_WK + 2048)
#define PREP_WO     (PREP_WV + 2048)         // 64x64
#define PREP_TOTAL  (PREP_WO + 4096)

__device__ __forceinline__ void tcast_body(
    const float* __restrict__ in, ushort* __restrict__ out,
    int K, int N, int bx, int by, int t)
{
    __shared__ float tile[32][33];
    int n0 = bx * 32, k0 = by * 32;
    int tx = t & 31, ty = t >> 5; // 32 x 8
#pragma unroll
    for (int i = 0; i < 32; i += 8)
        tile[ty + i][tx] = in[(size_t)(k0 + ty + i) * N + n0 + tx];
    __syncthreads();
#pragma unroll
    for (int i = 0; i < 32; i += 8)
        out[(size_t)(n0 + ty + i) * K + k0 + tx] = f2bf(tile[tx][ty + i]);
}

__global__ __launch_bounds__(256) void prep(
    const float* __restrict__ X,  const float* __restrict__ wq,
    const float* __restrict__ wk, const float* __restrict__ wv,
    const float* __restrict__ wo,
    ushort* __restrict__ Xb, ushort* __restrict__ WqkvT, ushort* __restrict__ Wot)
{
    int bid = blockIdx.x, t = threadIdx.x;
    if (bid < PREP_CAST) {
        int i = (bid * 256 + t) * 4;
        float4 v = *(const float4*)&X[i];
        ushort4 o = { f2bf(v.x), f2bf(v.y), f2bf(v.z), f2bf(v.w) };
        *(ushort4*)&Xb[i] = o;
    } else if (bid < PREP_WK) {
        int l = bid - PREP_WQ;
        tcast_body(wq, WqkvT, 2048, 2048, l & 63, l >> 6, t);
    } else if (bid < PREP_WV) {
        int l = bid - PREP_WK;
        tcast_body(wk, WqkvT + (size_t)2048 * 2048, 2048, 1024, l & 31, l >> 5, t);
    } else if (bid < PREP_WO) {
        int l = bid - PREP_WV;
        tcast_body(wv, WqkvT + (size_t)3072 * 2048, 2048, 1024, l & 31, l >> 5, t);
    } else {
        int l = bid - PREP_WO;
        tcast_body(wo, Wot, 2048, 2048, l & 63, l >> 6, t);
    }
}

// ---------------------------------------------------------------- GEMM: C = A @ Bt^T
// Phased-pipeline structure (T2+T3+T4+T5): BM=256, BN=128, BK=64, 8 waves (512 thr),
// ring-of-3 LDS K-tile buffers (144 KB). Tile T computes from ring[T%3] while tile
// T+2 stages into ring[(T+2)%3]. vmcnt(6) once per tile (counted).
template <typename OutT>
__global__ __launch_bounds__(512, 2) void gemm_bt2(
    const ushort* __restrict__ A, const ushort* __restrict__ Bt,
    OutT* __restrict__ C, int M, int N, int K)
{
    __shared__ __align__(16) ushort As[3][256 * 64];
    __shared__ __align__(16) ushort Bs[3][128 * 64];
    const int t = threadIdx.x;
    const int lane = t & 63, wave = t >> 6;
    const int quad = lane >> 4, l15 = lane & 15;
    const int m0 = blockIdx.y * 256, n0 = blockIdx.x * 128;
    const int wm = (wave >> 1) * 64;  // wave A-row base within 256
    const int wn = (wave & 1) * 64;   // wave B-row base within 128

    const f32x4 zv = {0.f, 0.f, 0.f, 0.f};
    f32x4 acc[4][4]; // [mf][nf], nf 0..1 phase0, 2..3 phase1
#pragma unroll
    for (int i = 0; i < 4; i++)
#pragma unroll
        for (int j = 0; j < 4; j++) acc[i][j] = zv;

    int arow[4], acol[4];
#pragma unroll
    for (int j = 0; j < 4; j++) {
        int p = (j * 512 + t) * 16;
        int l = p ^ (((p >> 9) & 1) << 5);
        arow[j] = l >> 7; acol[j] = (l & 127) >> 1;
    }
    int brow[2], bcol[2];
#pragma unroll
    for (int j = 0; j < 2; j++) {
        int p = (j * 512 + t) * 16;
        int l = p ^ (((p >> 9) & 1) << 5);
        brow[j] = l >> 7; bcol[j] = (l & 127) >> 1;
    }

    int aoff[4][2], boff[2][2][2];
#pragma unroll
    for (int mf = 0; mf < 4; mf++)
#pragma unroll
        for (int kk = 0; kk < 2; kk++)
            aoff[mf][kk] = swz_off(wm + mf * 16 + l15, kk * 64 + quad * 16);
#pragma unroll
    for (int q = 0; q < 2; q++)
#pragma unroll
        for (int nf = 0; nf < 2; nf++)
#pragma unroll
            for (int kk = 0; kk < 2; kk++)
                boff[q][nf][kk] = swz_off(wn + q * 32 + nf * 16 + l15, kk * 64 + quad * 16);

#define STAGE_A(j, slot, kk0) \
    gll16(&A[(size_t)(m0 + arow[j]) * K + (kk0) + acol[j]], &As[slot][0] + ((j) * 512 + t) * 8)
#define STAGE_B(j, slot, kk0) \
    gll16(&Bt[(size_t)(n0 + brow[j]) * K + (kk0) + bcol[j]], &Bs[slot][0] + ((j) * 512 + t) * 8)

    const int NT = K >> 6;

#pragma unroll
    for (int j = 0; j < 4; j++) STAGE_A(j, 0, 0);
#pragma unroll
    for (int j = 0; j < 2; j++) STAGE_B(j, 0, 0);
#pragma unroll
    for (int j = 0; j < 4; j++) STAGE_A(j, 1, 64);
#pragma unroll
    for (int j = 0; j < 2; j++) STAGE_B(j, 1, 64);
    asm volatile("s_waitcnt vmcnt(6)" ::: "memory");
    __builtin_amdgcn_s_barrier();

    int cur = 0;
    for (int T = 0; T < NT; T++) {
        const ushort* Ac = &As[cur][0];
        const ushort* Bc = &Bs[cur][0];
        int stg = cur + 2; if (stg >= 3) stg -= 3;
        const int k2 = (T + 2) << 6;
        const bool do_stage = (T + 2) < NT;

        // ---------- phase 0
        uint4 af[4][2], bf[2][2];
#pragma unroll
        for (int mf = 0; mf < 4; mf++)
#pragma unroll
            for (int kk = 0; kk < 2; kk++)
                af[mf][kk] = *(const uint4*)&Ac[aoff[mf][kk]];
#pragma unroll
        for (int nf = 0; nf < 2; nf++)
#pragma unroll
            for (int kk = 0; kk < 2; kk++)
                bf[nf][kk] = *(const uint4*)&Bc[boff[0][nf][kk]];
        if (do_stage) {
            STAGE_A(0, stg, k2); STAGE_A(1, stg, k2); STAGE_B(0, stg, k2);
        }
        __builtin_amdgcn_s_barrier();
        asm volatile("s_waitcnt lgkmcnt(0)" ::: "memory");
        __builtin_amdgcn_sched_barrier(0);
        __builtin_amdgcn_s_setprio(1);
#pragma unroll
        for (int mf = 0; mf < 4; mf++)
#pragma unroll
            for (int nf = 0; nf < 2; nf++)
#pragma unroll
                for (int kk = 0; kk < 2; kk++)
                    acc[mf][nf] = __builtin_amdgcn_mfma_f32_16x16x32_bf16(
                        as_bf8(af[mf][kk]), as_bf8(bf[nf][kk]), acc[mf][nf], 0, 0, 0);
        __builtin_amdgcn_s_setprio(0);
        __builtin_amdgcn_s_barrier();

        // ---------- phase 1
#pragma unroll
        for (int nf = 0; nf < 2; nf++)
#pragma unroll
            for (int kk = 0; kk < 2; kk++)
                bf[nf][kk] = *(const uint4*)&Bc[boff[1][nf][kk]];
        if (do_stage) {
            STAGE_A(2, stg, k2); STAGE_A(3, stg, k2); STAGE_B(1, stg, k2);
            asm volatile("s_waitcnt vmcnt(6)" ::: "memory"); // tile T+1 landed
        } else if (T + 2 == NT) {
            asm volatile("s_waitcnt vmcnt(0)" ::: "memory"); // epilogue drain
        }
        __builtin_amdgcn_s_barrier();
        asm volatile("s_waitcnt lgkmcnt(0)" ::: "memory");
        __builtin_amdgcn_sched_barrier(0);
        __builtin_amdgcn_s_setprio(1);
#pragma unroll
        for (int mf = 0; mf < 4; mf++)
#pragma unroll
            for (int nf = 0; nf < 2; nf++)
#pragma unroll
                for (int kk = 0; kk < 2; kk++)
                    acc[mf][2 + nf] = __builtin_amdgcn_mfma_f32_16x16x32_bf16(
                        as_bf8(af[mf][kk]), as_bf8(bf[nf][kk]), acc[mf][2 + nf], 0, 0, 0);
        __builtin_amdgcn_s_setprio(0);
        __builtin_amdgcn_s_barrier();

        cur++; if (cur == 3) cur = 0;
    }
#undef STAGE_A
#undef STAGE_B

#pragma unroll
    for (int mf = 0; mf < 4; mf++)
#pragma unroll
        for (int nf = 0; nf < 4; nf++)
#pragma unroll
            for (int r = 0; r < 4; r++) {
                int row = m0 + wm + mf * 16 + quad * 4 + r;
                int col = n0 + wn + nf * 16 + l15;
                store_el(&C[(size_t)row * N + col], acc[mf][nf][r]);
            }
}

// ------------------------------------------- per-head RMSNorm + RoPE, in place on QKV
// log2(e) folded into the Q scale so attention can use v_exp_f32 (2^x) directly.
__global__ __launch_bounds__(256) void norm_rope(
    ushort* __restrict__ qkv, const float* __restrict__ qw, const float* __restrict__ kw)
{
    int row = blockIdx.x;            // b*S + s
    int s = row & (SS - 1);
    int lane = threadIdx.x & 63, wave = threadIdx.x >> 6;
    int l = lane & 31, hsel = lane >> 5;
    float d0 = (float)(2 * l), d1 = d0 + 1.0f;
    float inv0 = expf(-d0 * (1.0f / 64.0f) * 9.210340371976184f);
    float inv1 = expf(-d1 * (1.0f / 64.0f) * 9.210340371976184f);
    float c0, s0, c1, s1;
    sincosf((float)s * inv0, &s0, &c0);
    sincosf((float)s * inv1, &s1, &c1);
    float qw0 = qw[2 * l], qw1 = qw[2 * l + 1], qy0 = qw[2 * l + 64], qy1 = qw[2 * l + 65];
    float kw0 = kw[2 * l], kw1 = kw[2 * l + 1], ky0 = kw[2 * l + 64], ky1 = kw[2 * l + 65];

#pragma unroll
    for (int pass = 0; pass < 3; pass++) {
        int h = pass * 8 + wave * 2 + hsel;
        ushort* p = qkv + (size_t)row * QKVW + h * 128;
        unsigned int ulo = *(const unsigned int*)&p[2 * l];
        unsigned int uhi = *(const unsigned int*)&p[2 * l + 64];
        float x0 = bf2f((ushort)ulo), x1 = bf2f((ushort)(ulo >> 16));
        float y0 = bf2f((ushort)uhi), y1 = bf2f((ushort)(uhi >> 16));
        float ssum = x0 * x0 + x1 * x1 + y0 * y0 + y1 * y1;
#pragma unroll
        for (int xm = 1; xm < 32; xm <<= 1) ssum += __shfl_xor(ssum, xm, 64);
        float r = rsqrtf(ssum * (1.0f / 128.0f) + 1e-6f);
        bool isq = (h < 16);
        float w0 = isq ? qw0 : kw0, w1 = isq ? qw1 : kw1;
        float v0 = isq ? qy0 : ky0, v1 = isq ? qy1 : ky1;
        // q scale = log2(e)/sqrt(128): scores land in log2 domain for exp2
        float sc = isq ? (0.08838834764831845f * 1.4426950408889634f) : 1.0f;
        float nx0 = w0 * (x0 * r), nx1 = w1 * (x1 * r);
        float ny0 = v0 * (y0 * r), ny1 = v1 * (y1 * r);
        float ox0 = (nx0 * c0 - ny0 * s0) * sc, ox1 = (nx1 * c1 - ny1 * s1) * sc;
        float oy0 = (ny0 * c0 + nx0 * s0) * sc, oy1 = (ny1 * c1 + nx1 * s1) * sc;
        *(unsigned int*)&p[2 * l]      = (unsigned int)f2bf(ox0) | ((unsigned int)f2bf(ox1) << 16);
        *(unsigned int*)&p[2 * l + 64] = (unsigned int)f2bf(oy0) | ((unsigned int)f2bf(oy1) << 16);
    }
}

// ---------------------------------------------------------------- flash attention
// Swapped QK^T (T12) + double-buffered K (T3/T4): K(t+1) staged via global_load_lds
// into Ks[cur^1] and V(t+1) reg-prefetched during tile t; the mid-tile barrier is a
// raw s_barrier + lgkmcnt(0) only, so the 8 vmem ops stay in flight across it and
// get a full tile of compute cover (drained by the next tile's __syncthreads).
// QK accumulators initialized with the additive mask; P = exp2(score) (log2e folded
// into Q). LDS: Ks 2x16K + Vt 16K + Madd 8K = 56 KB -> 2 blocks/CU.
__global__ __launch_bounds__(256, 2) void flash_attn(
    const ushort* __restrict__ qkv, const float* __restrict__ mask, ushort* __restrict__ O)
{
    __shared__ __align__(16) ushort Ks[2][64 * 128]; // [key][dchunk ^ (key&15)]
    __shared__ __align__(16) ushort Vt[128 * 64];    // [d][keychunk ^ (d&7)]
    __shared__ __align__(16) float  Madd[SS];        // (1-mask)*-1e30 per key
    const int t = threadIdx.x;
    const int lane = t & 63, wave = t >> 6;
    const int l31 = lane & 31, half = lane >> 5;
    const int b = blockIdx.z, h = blockIdx.y, q0 = blockIdx.x * 128;
    const int kh = h >> 1; // GQA

#pragma unroll
    for (int i = 0; i < 2; i++) {
        int idx = i * 1024 + t * 4;
        float4 mv = *(const float4*)&mask[b * SS + idx];
        float4 o = { (1.f - mv.x) * -1e30f, (1.f - mv.y) * -1e30f,
                     (1.f - mv.z) * -1e30f, (1.f - mv.w) * -1e30f };
        *(float4*)&Madd[idx] = o;
    }

    uint4 aq[8];
    {
        const ushort* qp = qkv + ((size_t)(b * SS + q0 + wave * 32 + l31)) * QKVW + h * 128 + half * 8;
#pragma unroll
        for (int kt = 0; kt < 8; kt++) aq[kt] = *(const uint4*)&qp[kt * 16];
    }
    f32x16 acc_o[4];
#pragma unroll
    for (int i = 0; i < 4; i++)
#pragma unroll
        for (int r = 0; r < 16; r++) acc_o[i][r] = 0.f;
    float lp[4] = {0.f, 0.f, 0.f, 0.f};

    const ushort* Kg = qkv + (size_t)b * SS * QKVW + 2048 + kh * 128;
    const ushort* Vg = qkv + (size_t)b * SS * QKVW + 3072 + kh * 128;

    const int vp = t & 31, vdc = t >> 5;
    uint4 vreg[4];
#define LOAD_V(K0)                                                                  \
    {                                                                               \
        _Pragma("unroll")                                                           \
        for (int pass = 0; pass < 2; pass++) {                                      \
            int d0 = (vdc + pass * 8) * 8;                                          \
            vreg[pass * 2 + 0] = *(const uint4*)&Vg[(size_t)((K0) + 2 * vp) * QKVW + d0];     \
            vreg[pass * 2 + 1] = *(const uint4*)&Vg[(size_t)((K0) + 2 * vp + 1) * QKVW + d0]; \
        }                                                                           \
    }
#define STAGE_K(K0, buf)                                                            \
    {                                                                               \
        _Pragma("unroll")                                                           \
        for (int i = 0; i < 4; i++) {                                               \
            int chunk = i * 256 + t;                                                \
            int row = chunk >> 4, cp = chunk & 15;                                  \
            int cl = cp ^ (row & 15);                                               \
            gll16(&Kg[(size_t)((K0) + row) * QKVW + cl * 8], &Ks[buf][chunk * 8]);  \
        }                                                                           \
    }

    STAGE_K(0, 0);
    LOAD_V(0);

    for (int k0 = 0; k0 < SS; k0 += 64) {
        const int cur = (k0 >> 6) & 1;
        // full drain: K(t)/V(t) (issued a full tile ago) landed; t-1 LDS reads done
        __syncthreads();
        // prefetch next tile: K via async LDS, V via regs (survive the raw barrier)
        if (k0 + 64 < SS) STAGE_K(k0 + 64, cur ^ 1);
        // V tile: transpose from vreg; slot for key-chunk c=(vp>>2) is c^(d&7)
#pragma unroll
        for (int pass = 0; pass < 2; pass++) {
            const ushort* pa_ = (const ushort*)&vreg[pass * 2 + 0];
            const ushort* pb_ = (const ushort*)&vreg[pass * 2 + 1];
            int d0 = (vdc + pass * 8) * 8;
#pragma unroll
            for (int j = 0; j < 8; j++) {
                int cp = (vp >> 2) ^ j;
                unsigned int v = (unsigned int)pa_[j] | ((unsigned int)pb_[j] << 16);
                *(unsigned int*)&Vt[(d0 + j) * 64 + cp * 8 + (vp & 3) * 2] = v;
            }
        }
        if (k0 + 64 < SS) LOAD_V(k0 + 64);
        asm volatile("s_waitcnt lgkmcnt(0)" ::: "memory"); // Vt writes visible
        __builtin_amdgcn_sched_barrier(0);
        __builtin_amdgcn_s_barrier();                      // no vmem drain

        // QK accumulators initialized with additive mask (saves the post-add)
        f32x16 sc[2];
#pragma unroll
        for (int nt = 0; nt < 2; nt++)
#pragma unroll
            for (int g = 0; g < 4; g++) {
                f32x4 em = *(const f32x4*)&Madd[k0 + nt * 32 + 4 * half + g * 8];
#pragma unroll
                for (int j = 0; j < 4; j++) sc[nt][g * 4 + j] = em[j];
            }
        __builtin_amdgcn_s_setprio(1);
#pragma unroll
        for (int nt = 0; nt < 2; nt++) {
#pragma unroll
            for (int kt = 0; kt < 8; kt++) {
                int cp = (kt * 2 + half) ^ (l31 & 15);
                uint4 bk = *(const uint4*)&Ks[cur][(nt * 32 + l31) * 128 + cp * 8];
                sc[nt] = __builtin_amdgcn_mfma_f32_32x32x16_bf16(
                    as_bf8(bk), as_bf8(aq[kt]), sc[nt], 0, 0, 0);
            }
        }
        __builtin_amdgcn_s_setprio(0);

        uint4 pa[4];
#pragma unroll
        for (int nt = 0; nt < 2; nt++) {
            float p[16];
#pragma unroll
            for (int r = 0; r < 16; r++) {
                float pv = __builtin_amdgcn_exp2f(sc[nt][r]);
                p[r] = pv;
                lp[r & 3] += pv;
            }
            unsigned int pk[8];
#pragma unroll
            for (int i = 0; i < 8; i++) pk[i] = cvtpk_bf16(p[2 * i], p[2 * i + 1]);
            auto sA = __builtin_amdgcn_permlane32_swap(pk[0], pk[2], false, false);
            auto sB = __builtin_amdgcn_permlane32_swap(pk[1], pk[3], false, false);
            auto sC = __builtin_amdgcn_permlane32_swap(pk[4], pk[6], false, false);
            auto sD = __builtin_amdgcn_permlane32_swap(pk[5], pk[7], false, false);
            uint4 f0, f1;
            f0.x = sA[0]; f0.y = sB[0]; f0.z = sA[1]; f0.w = sB[1];
            f1.x = sC[0]; f1.y = sD[0]; f1.z = sC[1]; f1.w = sD[1];
            pa[nt * 2 + 0] = f0;
            pa[nt * 2 + 1] = f1;
        }

        __builtin_amdgcn_s_setprio(1);
#pragma unroll
        for (int kt2 = 0; kt2 < 4; kt2++) {
            int kc = kt2 * 2 + half;
            int co = (kc ^ (l31 & 7)) * 8;
#pragma unroll
            for (int nt = 0; nt < 4; nt++) {
                uint4 bv = *(const uint4*)&Vt[(nt * 32 + l31) * 64 + co];
                acc_o[nt] = __builtin_amdgcn_mfma_f32_32x32x16_bf16(
                    as_bf8(pa[kt2]), as_bf8(bv), acc_o[nt], 0, 0, 0);
            }
        }
        __builtin_amdgcn_s_setprio(0);
    }
    float lsum = (lp[0] + lp[1]) + (lp[2] + lp[3]);
    lsum += __shfl_xor(lsum, 32, 64);
    float linv = 1.0f / lsum;
    float li[16];
#pragma unroll
    for (int r = 0; r < 16; r++)
        li[r] = __shfl(linv, (r & 3) + 8 * (r >> 2) + 4 * half, 64);
#pragma unroll
    for (int nt = 0; nt < 4; nt++)
#pragma unroll
        for (int r = 0; r < 16; r++) {
            int prow = (r & 3) + 8 * (r >> 2) + 4 * half;
            int qrow = q0 + wave * 32 + prow;
            int d = nt * 32 + l31;
            float v = acc_o[nt][r] * li[r];
            O[((size_t)(b * SS + qrow)) * (NHQ * DD) + h * 128 + d] = f2bf(v);
        }
}

// ---------------------------------------------------------------- launch
extern "C" void kernel_launch(void* const* d_in, const int* in_sizes, int n_in,
                              void* d_out, int out_size, void* d_ws, size_t ws_size,
                              hipStream_t stream)
{
    const float* X    = (const float*)d_in[0];
    const float* mask = (const float*)d_in[1];
    const float* wq   = (const float*)d_in[2];
    const float* wk   = (const float*)d_in[3];
    const float* wv   = (const float*)d_in[4];
    const float* wo   = (const float*)d_in[5];
    const float* qnw  = (const float*)d_in[6];
    const float* knw  = (const float*)d_in[7];
    float* out = (float*)d_out;

    const size_t M = (size_t)BB * SS; // 4096
    ushort* Xb    = (ushort*)d_ws;                       // 4096x2048
    ushort* WqkvT = Xb    + M * HID;                     // 4096x2048 (Wq^T|Wk^T|Wv^T rows)
    ushort* Wot   = WqkvT + (size_t)4096 * HID;          // 2048x2048
    ushort* QKV   = Wot   + (size_t)2048 * 2048;         // 4096x4096
    ushort* Obuf  = QKV   + M * QKVW;                    // 4096x2048

    prep<<<PREP_TOTAL, 256, 0, stream>>>(X, wq, wk, wv, wo, Xb, WqkvT, Wot);

    // fused QKV projection: (4096,2048) @ (4096,2048)^T -> (4096,4096)
    gemm_bt2<ushort><<<dim3(4096 / 128, 4096 / 256), 512, 0, stream>>>(Xb, WqkvT, QKV, 4096, 4096, 2048);

    norm_rope<<<(int)M, 256, 0, stream>>>(QKV, qnw, knw);

    flash_attn<<<dim3(SS / 128, NHQ, BB), 256, 0, stream>>>(QKV, mask, Obuf);

    // out projection: (4096,2048) @ (2048,2048)^T -> fp32 d_out
    gemm_bt2<float><<<dim3(2048 / 128, 4096 / 256), 512, 0, stream>>>(Obuf, Wot, out, 4096, 2048, 2048);
}